// Round 9
// baseline (53.274 us; speedup 1.0000x reference)
//
#include <hip/hip_runtime.h>
#include <hip/hip_bf16.h>
#include <cstdint>

typedef __bf16 bf16x8 __attribute__((ext_vector_type(8)));
typedef float  f32x4  __attribute__((ext_vector_type(4)));
typedef float  f32x2  __attribute__((ext_vector_type(2)));
typedef unsigned short ushort8v __attribute__((ext_vector_type(8)));

constexpr int RTOT  = 2304;          // 9 taps * 256 channels, r = k*256 + c
constexpr int NITER = 36;            // BK = 64 per iteration

#define WAITV4    asm volatile("s_waitcnt vmcnt(4)" ::: "memory")
#define WAITV0    asm volatile("s_waitcnt vmcnt(0)" ::: "memory")
#define WAITLGKM0 asm volatile("s_waitcnt lgkmcnt(0)" ::: "memory")
#define SCHEDB    __builtin_amdgcn_sched_barrier(0)

__device__ __forceinline__ f32x2 up2(unsigned u) {
    union { unsigned i; float f; } lo, hi;
    lo.i = u << 16; hi.i = u & 0xffff0000u;
    return (f32x2){lo.f, hi.f};
}

__device__ __forceinline__ void gload_lds16(const void* g, void* l) {
    __builtin_amdgcn_global_load_lds(
        (const __attribute__((address_space(1))) unsigned int*)g,
        (__attribute__((address_space(3))) unsigned int*)l, 16, 0, 0);
}

// ---- prep 1: x [4,256,64,64] f32 (NCHW) -> xh [4,64,64,256] bf16 (NHWC) ----
__global__ __launch_bounds__(256)
void nchw_to_nhwc_bf16(const float* __restrict__ x, __bf16* __restrict__ xh) {
    __shared__ unsigned short tile[256][70];
    const int tid = threadIdx.x;
    const int b = blockIdx.x >> 6;
    const int y = blockIdx.x & 63;
    const float* xp = x + (size_t)b * (256 * 4096) + y * 64;
    #pragma unroll 4
    for (int it = 0; it < 64; ++it) {
        const int ci = it * 4 + (tid >> 6);
        const int xi = tid & 63;
        __bf16 h = (__bf16)xp[(size_t)ci * 4096 + xi];
        tile[ci][xi] = *reinterpret_cast<unsigned short*>(&h);
    }
    __syncthreads();
    unsigned short* op = reinterpret_cast<unsigned short*>(xh) + ((size_t)b * 64 + y) * 64 * 256;
    #pragma unroll 4
    for (int it = 0; it < 64; ++it)
        op[(size_t)it * 256 + tid] = tile[tid][it];
}

// ---- prep 2: w [co][c][k] f32 -> wb [co][k*256+c] bf16 ----
__global__ __launch_bounds__(256)
void weight_prep(const float* __restrict__ w, __bf16* __restrict__ wb) {
    const int o = (blockIdx.x * 256 + threadIdx.x) * 4;
    const int co = o / 2304;
    const int rem = o - co * 2304;
    const int k = rem >> 8;
    const int c = rem & 255;
    union { ushort4 u; __bf16 h[4]; } pk;
    #pragma unroll
    for (int j = 0; j < 4; ++j)
        pk.h[j] = (__bf16)w[co * 2304 + (c + j) * 9 + k];
    *reinterpret_cast<ushort4*>(reinterpret_cast<unsigned short*>(wb) + o) = pk.u;
}

// ---- main: fused deformable implicit GEMM, BK=64, 16 waves, role-split ----
// Block = 64 wo x 256 co, 1024 threads / 16 waves (2M x 8N); wave slab 32(M) x 32(N).
// Grid = 256 -> 1 block/CU, 4 waves/SIMD. Iter i: tap k = i>>2, ch block (i&3)*64.
// Role split: waves 0-7 = A-gen (gathers + packed combine + ds_write, 2-deep);
//             waves 8-15 = B staging (4 gload_lds/iter into 3-slot ring, 2-deep).
// All waves: 8 ds_read_b128 + 8 MFMA per iter. Pre-barrier wait = vmcnt(4) for BOTH
// roles (leaves own 4 newest loads in flight) -> no staging latency on critical path.
__global__ __launch_bounds__(1024, 1)
void deform_gemm_nhwc(const float* __restrict__ off, const __bf16* __restrict__ xh,
                      const __bf16* __restrict__ wb, float* __restrict__ out) {
    __shared__ float4 s_w[64 * 9];
    __shared__ int4   s_a[64 * 9];
    __shared__ unsigned short sA[2][64 * 64];    // [buf][p*64 + ch]
    __shared__ unsigned short sB[3][256 * 64];   // [slot][co*64 + ch]

    const int tid  = threadIdx.x;
    const int lane = tid & 63;
    const int wv   = tid >> 6;               // 0..15
    const int wm   = wv >> 3;                // M-half 0..1
    const int wn   = wv & 7;                 // N-eighth 0..7
    const int fr   = lane & 15;
    const int fq   = lane >> 4;
    const bool isA = (wv < 8);

    const int bs = ((blockIdx.x & 7) << 5) | (blockIdx.x >> 3);  // bijective XCD swizzle
    const int b  = bs >> 6;
    const int ho = bs & 63;

    // ---- per-(k, p) bilinear metadata (9 taps x 64 positions) ----
    for (int i = tid; i < 576; i += 1024) {
        const int k = i >> 6, p = i & 63;
        const int kh = k / 3, kw = k - kh * 3;
        const float dy = off[(((b * 18) + 2 * k    ) * 64 + ho) * 64 + p];
        const float dx = off[(((b * 18) + 2 * k + 1) * 64 + ho) * 64 + p];
        const float sy = (float)(ho - 1 + kh) + dy;
        const float sx = (float)(p  - 1 + kw) + dx;
        const float y0f = floorf(sy), x0f = floorf(sx);
        const float fy = sy - y0f, fx = sx - x0f;
        const int y0 = (int)y0f, x0 = (int)x0f;
        const int y1 = y0 + 1, x1 = x0 + 1;
        const bool vy0 = (unsigned)y0 < 64u, vy1 = (unsigned)y1 < 64u;
        const bool vx0 = (unsigned)x0 < 64u, vx1 = (unsigned)x1 < 64u;
        const int y0c = min(max(y0, 0), 63), y1c = min(max(y1, 0), 63);
        const int x0c = min(max(x0, 0), 63), x1c = min(max(x1, 0), 63);
        float4 wt;
        wt.x = (1.f - fy) * (1.f - fx) * ((vy0 & vx0) ? 1.f : 0.f);
        wt.y = (1.f - fy) * fx         * ((vy0 & vx1) ? 1.f : 0.f);
        wt.z = fy * (1.f - fx)         * ((vy1 & vx0) ? 1.f : 0.f);
        wt.w = fy * fx                 * ((vy1 & vx1) ? 1.f : 0.f);
        s_w[i] = wt;
        s_a[i] = make_int4((y0c << 6) + x0c, (y0c << 6) + x1c,
                           (y1c << 6) + x0c, (y1c << 6) + x1c);
    }

    f32x4 acc[2][2];
    #pragma unroll
    for (int mf = 0; mf < 2; ++mf)
        #pragma unroll
        for (int nf = 0; nf < 2; ++nf)
            acc[mf][nf] = (f32x4){0.f, 0.f, 0.f, 0.f};

    const __bf16* xb = xh + ((size_t)b << 20);
    // A-gen mapping (waves 0-7): 512 threads = 64 positions x 8 channel-octets
    const int atid = tid & 511;
    const int p    = atid >> 3;              // 0..63
    const int oct  = atid & 7;               // c = oct*8 within the 64-ch block
    const int aw_off = (p << 6) + ((oct ^ (p & 7)) << 3);
    const char* base_lane = (const char*)xb + (oct << 4);

    // B-stage mapping (waves 8-15): wave w8 stages rows [w8*32, w8*32+32)
    const int w8 = wv & 7;
    const __bf16* gpB[4];
    int bofs[4];
    #pragma unroll
    for (int q = 0; q < 4; ++q) {
        const int row = (w8 << 5) + (q << 3) + (lane >> 3);
        gpB[q] = wb + (size_t)row * RTOT + (((lane & 7) ^ (lane >> 3)) << 3);
        bofs[q] = ((w8 << 5) + (q << 3)) << 6;
    }

    // fragment-read swizzled unit offsets (elems) for K32 halves
    const int ua0 = ((0 + fq) ^ (fr & 7)) << 3;
    const int ua1 = ((4 + fq) ^ (fr & 7)) << 3;

    __syncthreads();  // meta ready

    float4 wt_k;
    uint4 ga0, ga1, ga2, ga3;
    const char *aK0, *aK1, *aK2, *aK3;

    // ---- prologue ----
    if (isA) {
        wt_k = s_w[p];                       // tap 0
        const int4 sa = s_a[p];
        aK0 = base_lane + ((size_t)sa.x << 9);
        aK1 = base_lane + ((size_t)sa.y << 9);
        aK2 = base_lane + ((size_t)sa.z << 9);
        aK3 = base_lane + ((size_t)sa.w << 9);
        ga0 = *reinterpret_cast<const uint4*>(aK0);
        ga1 = *reinterpret_cast<const uint4*>(aK1);
        ga2 = *reinterpret_cast<const uint4*>(aK2);
        ga3 = *reinterpret_cast<const uint4*>(aK3);
        WAITV0;
        {
            const unsigned* w0 = reinterpret_cast<const unsigned*>(&ga0);
            const unsigned* w1 = reinterpret_cast<const unsigned*>(&ga1);
            const unsigned* w2 = reinterpret_cast<const unsigned*>(&ga2);
            const unsigned* w3 = reinterpret_cast<const unsigned*>(&ga3);
            union { ushort8v u; __bf16 h[8]; } pk;
            #pragma unroll
            for (int jp = 0; jp < 4; ++jp) {
                f32x2 s = up2(w0[jp]) * wt_k.x + up2(w1[jp]) * wt_k.y
                        + up2(w2[jp]) * wt_k.z + up2(w3[jp]) * wt_k.w;
                pk.h[2 * jp]     = (__bf16)s.x;
                pk.h[2 * jp + 1] = (__bf16)s.y;
            }
            *reinterpret_cast<ushort8v*>(&sA[0][aw_off]) = pk.u;
        }
        // issue A(1): same tap, channel block 1 (byte offset 128)
        ga0 = *reinterpret_cast<const uint4*>(aK0 + 128);
        ga1 = *reinterpret_cast<const uint4*>(aK1 + 128);
        ga2 = *reinterpret_cast<const uint4*>(aK2 + 128);
        ga3 = *reinterpret_cast<const uint4*>(aK3 + 128);
    } else {
        #pragma unroll
        for (int q = 0; q < 4; ++q) gload_lds16(gpB[q], &sB[0][bofs[q]]);
        #pragma unroll
        for (int q = 0; q < 4; ++q) gload_lds16(gpB[q] + 64, &sB[1][bofs[q]]);
        WAITV4;    // B(0) landed; B(1) stays in flight
    }
    SCHEDB;
    WAITLGKM0;
    __builtin_amdgcn_s_barrier();
    SCHEDB;

    // ---- main loop: 36 iterations of BK=64 ----
    #pragma unroll 12
    for (int i = 0; i < NITER; ++i) {
        const unsigned short* sAc = sA[i & 1];
        const unsigned short* sBc = sB[i % 3];
        unsigned short* sBn = const_cast<unsigned short*>(sB[(i + 2) % 3]);

        // 1) fragment reads (8 x ds_read_b128)
        bf16x8 a0[2], a1[2], b0[2], b1[2];
        #pragma unroll
        for (int mf = 0; mf < 2; ++mf) {
            const int ar = (wm << 5) + mf * 16 + fr;
            a0[mf] = *reinterpret_cast<const bf16x8*>(&sAc[(ar << 6) + ua0]);
            a1[mf] = *reinterpret_cast<const bf16x8*>(&sAc[(ar << 6) + ua1]);
        }
        #pragma unroll
        for (int nf = 0; nf < 2; ++nf) {
            const int br = (wn << 5) + nf * 16 + fr;
            b0[nf] = *reinterpret_cast<const bf16x8*>(&sBc[(br << 6) + ua0]);
            b1[nf] = *reinterpret_cast<const bf16x8*>(&sBc[(br << 6) + ua1]);
        }

        // 2) B-waves: stage B(i+2) (wb padded past RTOT so tail reads stay in-bounds)
        if (!isA) {
            #pragma unroll
            for (int q = 0; q < 4; ++q)
                gload_lds16(gpB[q] + (size_t)(i + 2) * 64, &sBn[bofs[q]]);
        }
        SCHEDB;

        // 3) MFMA K-half 0
        __builtin_amdgcn_s_setprio(1);
        #pragma unroll
        for (int mf = 0; mf < 2; ++mf)
            #pragma unroll
            for (int nf = 0; nf < 2; ++nf)
                acc[mf][nf] = __builtin_amdgcn_mfma_f32_16x16x32_bf16(a0[mf], b0[nf], acc[mf][nf], 0, 0, 0);
        __builtin_amdgcn_s_setprio(0);

        // 4) A-waves: combine A(i+1) (auto counted-vmcnt on ga deps), write other buffer
        if (isA && i < NITER - 1) {
            unsigned short* sAn = const_cast<unsigned short*>(sA[(i + 1) & 1]);
            const unsigned* w0 = reinterpret_cast<const unsigned*>(&ga0);
            const unsigned* w1 = reinterpret_cast<const unsigned*>(&ga1);
            const unsigned* w2 = reinterpret_cast<const unsigned*>(&ga2);
            const unsigned* w3 = reinterpret_cast<const unsigned*>(&ga3);
            union { ushort8v u; __bf16 h[8]; } pk;
            #pragma unroll
            for (int jp = 0; jp < 4; ++jp) {
                f32x2 s = up2(w0[jp]) * wt_k.x + up2(w1[jp]) * wt_k.y
                        + up2(w2[jp]) * wt_k.z + up2(w3[jp]) * wt_k.w;
                pk.h[2 * jp]     = (__bf16)s.x;
                pk.h[2 * jp + 1] = (__bf16)s.y;
            }
            *reinterpret_cast<ushort8v*>(&sAn[aw_off]) = pk.u;
        }
        SCHEDB;

        // 5) A-waves: issue A(i+2); tap meta reload when (i+2)%4 == 0
        if (isA && i < NITER - 2) {
            const int ia = i + 2;
            if ((ia & 3) == 0) {
                const int kk = ia >> 2;
                wt_k = s_w[(kk << 6) + p];
                const int4 sa = s_a[(kk << 6) + p];
                aK0 = base_lane + ((size_t)sa.x << 9);
                aK1 = base_lane + ((size_t)sa.y << 9);
                aK2 = base_lane + ((size_t)sa.z << 9);
                aK3 = base_lane + ((size_t)sa.w << 9);
            }
            const int cb = (ia & 3) << 7;    // channel-block byte offset within the tap
            ga0 = *reinterpret_cast<const uint4*>(aK0 + cb);
            ga1 = *reinterpret_cast<const uint4*>(aK1 + cb);
            ga2 = *reinterpret_cast<const uint4*>(aK2 + cb);
            ga3 = *reinterpret_cast<const uint4*>(aK3 + cb);
        }
        SCHEDB;

        // 6) MFMA K-half 1
        __builtin_amdgcn_s_setprio(1);
        #pragma unroll
        for (int mf = 0; mf < 2; ++mf)
            #pragma unroll
            for (int nf = 0; nf < 2; ++nf)
                acc[mf][nf] = __builtin_amdgcn_mfma_f32_16x16x32_bf16(a1[mf], b1[nf], acc[mf][nf], 0, 0, 0);
        __builtin_amdgcn_s_setprio(0);

        // 7) uniform counted wait: each wave leaves its own 4 newest loads in flight
        //    (A-waves: ga(i+2); B-waves: B(i+2) gload_lds). Older loads drained.
        WAITV4;
        WAITLGKM0;
        __builtin_amdgcn_s_barrier();
        SCHEDB;
    }

    // ---- epilogue: rows m = wm*32 + mf*16 + fq*4 + j, cols n = wn*32 + nf*16 + fr ----
    float* ob = out + (size_t)b * (256 * 4096) + (ho << 6);
    #pragma unroll
    for (int nf = 0; nf < 2; ++nf) {
        const int n = (wn << 5) + nf * 16 + fr;
        #pragma unroll
        for (int mf = 0; mf < 2; ++mf) {
            const int m = (wm << 5) + mf * 16 + (fq << 2);
            *reinterpret_cast<f32x4*>(&ob[(size_t)n * 4096 + m]) = acc[mf][nf];
        }
    }
}

// ---- fallback (ws too small): convert-on-the-fly weights, NCHW gathers ----
__global__ __launch_bounds__(256, 2)
void deform_gemm_fb(const float* __restrict__ x, const float* __restrict__ off,
                    const float* __restrict__ wf, float* __restrict__ out) {
    __shared__ float4 s_w[32 * 9];
    __shared__ int4   s_a[32 * 9];
    __shared__ unsigned short sA[2][32 * 32];
    __shared__ unsigned short sB[2][256 * 32];

    const int tid  = threadIdx.x;
    const int lane = tid & 63;
    const int wv   = tid >> 6;
    const int fr   = lane & 15;
    const int fq   = lane >> 4;
    const int bs  = ((blockIdx.x & 7) << 6) | (blockIdx.x >> 3);
    const int b   = bs >> 7;
    const int ho  = (bs >> 1) & 63;
    const int wo0 = (bs & 1) << 5;

    for (int i = tid; i < 32 * 9; i += 256) {
        const int k = i >> 5, p = i & 31, wo = wo0 + p;
        const int kh = k / 3, kw = k - kh * 3;
        const float dy = off[(((b * 18) + 2 * k    ) * 64 + ho) * 64 + wo];
        const float dx = off[(((b * 18) + 2 * k + 1) * 64 + ho) * 64 + wo];
        const float sy = (float)(ho - 1 + kh) + dy;
        const float sx = (float)(wo - 1 + kw) + dx;
        const float y0f = floorf(sy), x0f = floorf(sx);
        const float fy = sy - y0f, fx = sx - x0f;
        const int y0 = (int)y0f, x0 = (int)x0f;
        const int y1 = y0 + 1, x1 = x0 + 1;
        const bool vy0 = (unsigned)y0 < 64u, vy1 = (unsigned)y1 < 64u;
        const bool vx0 = (unsigned)x0 < 64u, vx1 = (unsigned)x1 < 64u;
        const int y0c = min(max(y0, 0), 63), y1c = min(max(y1, 0), 63);
        const int x0c = min(max(x0, 0), 63), x1c = min(max(x1, 0), 63);
        float4 wt;
        wt.x = (1.f - fy) * (1.f - fx) * ((vy0 & vx0) ? 1.f : 0.f);
        wt.y = (1.f - fy) * fx         * ((vy0 & vx1) ? 1.f : 0.f);
        wt.z = fy * (1.f - fx)         * ((vy1 & vx0) ? 1.f : 0.f);
        wt.w = fy * fx                 * ((vy1 & vx1) ? 1.f : 0.f);
        s_w[i] = wt;
        s_a[i] = make_int4((y0c << 6) + x0c, (y0c << 6) + x1c,
                           (y1c << 6) + x0c, (y1c << 6) + x1c);
    }

    f32x4 acc[2][4];
    #pragma unroll
    for (int mf = 0; mf < 2; ++mf)
        #pragma unroll
        for (int nf = 0; nf < 4; ++nf)
            acc[mf][nf] = (f32x4){0.f, 0.f, 0.f, 0.f};

    const float* xb = x + (size_t)b * (256 * 4096);
    const int p  = tid & 31;
    const int rq = tid >> 5;
    const int aw_off = (p << 5) + ((((rq >> 1) ^ ((p >> 1) & 3)) << 3)) + ((rq & 1) << 2);

    int brow[4], bcol[4];
    #pragma unroll
    for (int q = 0; q < 4; ++q) {
        brow[q] = (wv << 6) + (q << 4) + (lane >> 2);
        bcol[q] = ((lane & 3) ^ ((brow[q] >> 1) & 3)) << 3;
    }
    const int bphys = (lane & 3) << 3;

    __syncthreads();

    for (int t = 0; t < 72; ++t) {
        const int cur = t & 1;
        const int r0 = t * 32;
        union { ushort4 u; __bf16 h[4]; } pk;
        #pragma unroll
        for (int j = 0; j < 4; ++j) {
            const int r = r0 + rq * 4 + j;
            const int c = r / 9, k = r - c * 9;
            const float4 wt = s_w[(k << 5) + p];
            const int4 ad = s_a[(k << 5) + p];
            const float* xp = xb + (c << 12);
            pk.h[j] = (__bf16)(wt.x * xp[ad.x] + wt.y * xp[ad.y]
                             + wt.z * xp[ad.z] + wt.w * xp[ad.w]);
        }
        *reinterpret_cast<ushort4*>(&sA[cur][aw_off]) = pk.u;
        #pragma unroll
        for (int q = 0; q < 4; ++q) {
            const float4* s = reinterpret_cast<const float4*>(wf + (size_t)brow[q] * RTOT + r0 + bcol[q]);
            float4 f0 = s[0], f1 = s[1];
            union { uint4 u; __bf16 h[8]; } ub;
            ub.h[0]=(__bf16)f0.x; ub.h[1]=(__bf16)f0.y; ub.h[2]=(__bf16)f0.z; ub.h[3]=(__bf16)f0.w;
            ub.h[4]=(__bf16)f1.x; ub.h[5]=(__bf16)f1.y; ub.h[6]=(__bf16)f1.z; ub.h[7]=(__bf16)f1.w;
            *reinterpret_cast<uint4*>(&sB[cur][(brow[q] << 5) + bphys]) = ub.u;
        }
        __syncthreads();
        bf16x8 af[2], bfr[4];
        #pragma unroll
        for (int mf = 0; mf < 2; ++mf) {
            const int row = mf * 16 + fr;
            af[mf] = *reinterpret_cast<const bf16x8*>(&sA[cur][(row << 5) + ((fq ^ ((row >> 1) & 3)) << 3)]);
        }
        #pragma unroll
        for (int nf = 0; nf < 4; ++nf) {
            const int row = (wv << 6) + nf * 16 + fr;
            bfr[nf] = *reinterpret_cast<const bf16x8*>(&sB[cur][(row << 5) + ((fq ^ ((row >> 1) & 3)) << 3)]);
        }
        #pragma unroll
        for (int mf = 0; mf < 2; ++mf)
            #pragma unroll
            for (int nf = 0; nf < 4; ++nf)
                acc[mf][nf] = __builtin_amdgcn_mfma_f32_16x16x32_bf16(af[mf], bfr[nf], acc[mf][nf], 0, 0, 0);
        __syncthreads();
    }

    float* ob = out + (size_t)b * (256 * 4096) + (ho << 6) + wo0;
    #pragma unroll
    for (int nf = 0; nf < 4; ++nf) {
        const int n = (wv << 6) + nf * 16 + fr;
        #pragma unroll
        for (int mf = 0; mf < 2; ++mf) {
            const int m = mf * 16 + (fq << 2);
            *reinterpret_cast<f32x4*>(&ob[(size_t)n * 4096 + m]) = acc[mf][nf];
        }
    }
}

extern "C" void kernel_launch(void* const* d_in, const int* in_sizes, int n_in,
                              void* d_out, int out_size, void* d_ws, size_t ws_size,
                              hipStream_t stream) {
    const float* x   = (const float*)d_in[0];
    const float* off = (const float*)d_in[1];
    const float* w   = (const float*)d_in[2];
    float* out = (float*)d_out;

    const size_t xh_bytes = (size_t)4 * 64 * 64 * 256 * sizeof(__bf16);   // 8.4 MB
    const size_t wb_bytes = (size_t)256 * RTOT * sizeof(__bf16);          // 1.18 MB
    const size_t pad_bytes = 8192;                                        // B tail over-read pad
    if (ws_size >= xh_bytes + wb_bytes + pad_bytes) {
        __bf16* xh = (__bf16*)d_ws;
        __bf16* wb = (__bf16*)((char*)d_ws + xh_bytes);
        nchw_to_nhwc_bf16<<<dim3(256), dim3(256), 0, stream>>>(x, xh);
        weight_prep<<<dim3(576), dim3(256), 0, stream>>>(w, wb);
        deform_gemm_nhwc<<<dim3(256), dim3(1024), 0, stream>>>(off, xh, wb, out);
    } else {
        deform_gemm_fb<<<dim3(512), dim3(256), 0, stream>>>(x, off, w, out);
    }
}